// Round 2
// baseline (1314.548 us; speedup 1.0000x reference)
//
#include <hip/hip_runtime.h>

#define N_PRE 1024
#define N_POST 2048
#define SEQ_LEN 4096

// Reference-verified numerics (R11 PASS): per C element two fp32 segment
// chains k in [0,512) and [512,1024), ascending, single accumulator each,
// combined rn(S1+S2). stim in {0,1} -> products exact -> FMA == mul+add.
// Scan: v = rn(rn(v*0.9f) + c), fire >= 1.0f, reset 0. DO NOT REORDER.
// v3: the two segments are computed by SEPARATE blocks (blockIdx.z) into
// C0/C1; the rn(S1+S2) combine happens in the scan's staging phase.
// Arithmetic is bit-identical to v2.
#define KSPLIT 512

__device__ __forceinline__ float opaque(float x) {
  asm volatile("" : "+v"(x));
  return x;
}

__device__ __forceinline__ float load_dyn(const void* p, size_t idx, bool isbf) {
  if (isbf) {
    const unsigned short b = ((const unsigned short*)p)[idx];
    return __uint_as_float(((unsigned int)b) << 16);
  }
  return ((const float*)p)[idx];
}

// Input-dtype sniff (established: weights fp32, stim bf16; kept for safety).
__device__ __forceinline__ int sniff_flags(const void* W, const void* S, int tid,
                                           int* flags_sh) {
  if (tid < 64) {
    const unsigned short* uw = (const unsigned short*)W;
    const float f = fabsf(__uint_as_float(((unsigned int)uw[tid * 2]) << 16));
    const bool big = !(f < 64.f);
    const unsigned long long wb = __ballot(big);
    const unsigned short* us = (const unsigned short*)S;
    int hit = 0;
    for (int j = 0; j < 64; ++j) hit |= (us[tid * 128 + 2 * j] == 0x3F80u) ? 1 : 0;
    const unsigned long long sb = __ballot(hit != 0);
    if (tid == 0) *flags_sh = ((wb == 0ull) ? 1 : 0) | ((sb != 0ull) ? 2 : 0);
  }
  __syncthreads();
  return *flags_sh;
}

// ---------------- GEMM v3: 128x64 tile, 8x8 microtile, split-K over z -------
// 128 threads/block, grid (ct/64, 16, 2) = 2048 blocks -> 8 blocks/CU,
// 16 waves/CU (was 2 blocks/CU). Single acc[8][8] (64 regs) per block since
// each block owns one 512-segment. B-staging packed to b128 writes (kills the
// 8-way bank conflict of the scalar bf16 stores).
__global__ __launch_bounds__(128, 4) void snn_gemm_v3(const void* __restrict__ W,
                                                      const void* __restrict__ S,
                                                      float* __restrict__ C,
                                                      int t0, int ct) {
  __shared__ float As[16][132];  // [k][m], row 528B: 16B-aligned, 132%32=4
  __shared__ float Bs[16][68];   // [k][t], row 272B: 16B-aligned, 68%32=4
  __shared__ int flags_sh;
  const int tid = threadIdx.x;
  const int fl = sniff_flags(W, S, tid, &flags_sh);
  const bool w_bf = (fl & 1) != 0;
  const bool s_bf = (fl & 2) != 0;

  const int tx = tid & 7;   // t dim, 8 cols each
  const int ty = tid >> 3;  // m dim (0..15), 8 rows each
  const int m0 = blockIdx.y * 128;
  const int nl0 = blockIdx.x * 64;
  const int kbeg = (int)blockIdx.z * KSPLIT;

  float acc[8][8] = {{0.f}};

  for (int k0 = kbeg; k0 < kbeg + KSPLIT; k0 += 16) {
    // ---- stage A: W[m0..+128][k0..+16] -> As[k][m] ----
    if (!w_bf) {
      const float* Wf = (const float*)W;
      const int c4 = (tid & 3) * 4;
      const int mr = tid >> 2;  // 0..31
#pragma unroll
      for (int h = 0; h < 4; ++h) {
        const int m = mr + 32 * h;
        const float4 va = *(const float4*)&Wf[(size_t)(m0 + m) * N_PRE + k0 + c4];
        As[c4 + 0][m] = va.x; As[c4 + 1][m] = va.y;
        As[c4 + 2][m] = va.z; As[c4 + 3][m] = va.w;
      }
    } else {
#pragma unroll
      for (int e = 0; e < 16; ++e) {
        const int idx = tid * 16 + e;
        const int m = idx >> 4, c = idx & 15;
        As[c][m] = load_dyn(W, (size_t)(m0 + m) * N_PRE + k0 + c, true);
      }
    }
    // ---- stage B: S[k0..+16][t0+nl0..+64] -> Bs[k][t], b128 writes ----
    {
      const int r = tid >> 3;        // 0..15
      const int c8 = (tid & 7) * 8;  // 0..56
      if (s_bf) {
        const unsigned short* Sb = (const unsigned short*)S;
        const uint4 u =
            *(const uint4*)&Sb[(size_t)(k0 + r) * SEQ_LEN + t0 + nl0 + c8];
        *(float4*)&Bs[r][c8] = make_float4(
            __uint_as_float(u.x << 16), __uint_as_float(u.x & 0xFFFF0000u),
            __uint_as_float(u.y << 16), __uint_as_float(u.y & 0xFFFF0000u));
        *(float4*)&Bs[r][c8 + 4] = make_float4(
            __uint_as_float(u.z << 16), __uint_as_float(u.z & 0xFFFF0000u),
            __uint_as_float(u.w << 16), __uint_as_float(u.w & 0xFFFF0000u));
      } else {
        const float* Sf = (const float*)S;
        const size_t base = (size_t)(k0 + r) * SEQ_LEN + t0 + nl0 + c8;
        *(float4*)&Bs[r][c8] = *(const float4*)&Sf[base];
        *(float4*)&Bs[r][c8 + 4] = *(const float4*)&Sf[base + 4];
      }
    }
    __syncthreads();
#pragma unroll
    for (int k = 0; k < 16; ++k) {
      float a[8], b[8];
      *(float4*)&a[0] = *(const float4*)&As[k][ty * 8];
      *(float4*)&a[4] = *(const float4*)&As[k][ty * 8 + 4];
      *(float4*)&b[0] = *(const float4*)&Bs[k][tx * 8];
      *(float4*)&b[4] = *(const float4*)&Bs[k][tx * 8 + 4];
#pragma unroll
      for (int i = 0; i < 8; ++i)
#pragma unroll
        for (int j = 0; j < 8; ++j)
          acc[i][j] += a[i] * b[j];  // exact product: add-chain only
    }
    __syncthreads();
  }

  float* Cseg = C + (size_t)blockIdx.z * N_POST * (size_t)ct;
#pragma unroll
  for (int i = 0; i < 8; ++i) {
    float* dst = &Cseg[(size_t)(m0 + ty * 8 + i) * ct + nl0 + tx * 8];
    *(float4*)&dst[0] = make_float4(acc[i][0], acc[i][1], acc[i][2], acc[i][3]);
    *(float4*)&dst[4] = make_float4(acc[i][4], acc[i][5], acc[i][6], acc[i][7]);
  }
}

// ---------------- Scan v3: single-wave blocks, 8 neurons, no barriers -------
// 256 blocks x 64 threads. Wave-lockstep makes LDS cross-lane coherent
// without __syncthreads. Prefetch loads issued BEFORE the scan chain,
// ds_writes AFTER it (latency hides under the 1024-cyc chain). The combine
// c = rn(C0 + C1) == rn(S1+S2) happens here, off the critical v-chain.
// Outputs stored directly from the 8 scan lanes (sequential 16B per row;
// L2 merges into full lines).
#define SCAN_R 8
#define SCAN_T 64
#define SCAN_P 68  // row stride 272B: 16B-aligned, 68%32=4 bank spread
__global__ __launch_bounds__(64) void snn_scan_v3(const float* __restrict__ C,
                                                  float* __restrict__ spk,
                                                  float* __restrict__ vout,
                                                  float* __restrict__ v_carry,
                                                  int t0, int ct, int first) {
  __shared__ float c_t[2][SCAN_R][SCAN_P];
  const int l = threadIdx.x;
  const int n0 = blockIdx.x * SCAN_R;
  const float* C1 = C + (size_t)N_POST * (size_t)ct;

  float v = 0.0f;
  if (l < SCAN_R && !first) v = v_carry[n0 + l];

  const int r0 = l >> 4;        // 0..3
  const int c4 = (l & 15) * 4;  // 0..60
  const int ntiles = ct / SCAN_T;

  // prologue: stage tile 0 (combine S1+S2 during staging)
#pragma unroll
  for (int h = 0; h < 2; ++h) {
    const int r = r0 + 4 * h;
    const size_t g = (size_t)(n0 + r) * ct + c4;
    const float4 a = *(const float4*)&C[g];
    const float4 b = *(const float4*)&C1[g];
    *(float4*)&c_t[0][r][c4] =
        make_float4(a.x + b.x, a.y + b.y, a.z + b.z, a.w + b.w);
  }

  int buf = 0;
  for (int it = 0; it < ntiles; ++it) {
    // issue next-tile loads now (complete under the scan chain)
    float4 pa[2], pb[2];
    const bool pf = (it + 1 < ntiles);
    if (pf) {
#pragma unroll
      for (int h = 0; h < 2; ++h) {
        const int r = r0 + 4 * h;
        const size_t g = (size_t)(n0 + r) * ct + (size_t)(it + 1) * SCAN_T + c4;
        pa[h] = *(const float4*)&C[g];
        pb[h] = *(const float4*)&C1[g];
      }
    }
    if (l < SCAN_R) {
      const size_t gout = (size_t)(n0 + l) * SEQ_LEN + t0 + (size_t)it * SCAN_T;
#pragma unroll
      for (int g = 0; g < SCAN_T / 16; ++g) {
        float c[16];
        *(float4*)&c[0] = *(const float4*)&c_t[buf][l][g * 16];
        *(float4*)&c[4] = *(const float4*)&c_t[buf][l][g * 16 + 4];
        *(float4*)&c[8] = *(const float4*)&c_t[buf][l][g * 16 + 8];
        *(float4*)&c[12] = *(const float4*)&c_t[buf][l][g * 16 + 12];
        float s[16], vv[16];
#pragma unroll
        for (int k = 0; k < 16; ++k) {
          const float leak = opaque(v * 0.9f);  // rn(v*0.9f)
          v = leak + c[k];                      // rn(+c)
          const bool fired = (v >= 1.0f);
          s[k] = fired ? 1.0f : 0.0f;
          v = fired ? 0.0f : v;
          vv[k] = v;
        }
#pragma unroll
        for (int q = 0; q < 4; ++q) {
          *(float4*)&spk[gout + g * 16 + q * 4] =
              make_float4(s[q * 4], s[q * 4 + 1], s[q * 4 + 2], s[q * 4 + 3]);
          *(float4*)&vout[gout + g * 16 + q * 4] =
              make_float4(vv[q * 4], vv[q * 4 + 1], vv[q * 4 + 2], vv[q * 4 + 3]);
        }
      }
    }
    // land the prefetch into the other buffer (vmcnt wait happens here,
    // after the chain, not before it)
    if (pf) {
#pragma unroll
      for (int h = 0; h < 2; ++h) {
        const int r = r0 + 4 * h;
        *(float4*)&c_t[buf ^ 1][r][c4] =
            make_float4(pa[h].x + pb[h].x, pa[h].y + pb[h].y, pa[h].z + pb[h].z,
                        pa[h].w + pb[h].w);
      }
    }
    buf ^= 1;
  }
  if (l < SCAN_R) v_carry[n0 + l] = v;
}

// ---------------- fused fallback (ws too small), same [512|512] chain -------
__global__ __launch_bounds__(256) void snn_fused_blis(const void* __restrict__ W,
                                                      const void* __restrict__ S,
                                                      float* __restrict__ spk,
                                                      float* __restrict__ vout) {
  __shared__ float As[16][68];
  __shared__ float Bs[16][68];
  __shared__ float Ct[64][65];
  __shared__ float vsh[64];
  __shared__ int flags_sh;
  const int tid = threadIdx.x;
  const int fl = sniff_flags(W, S, tid, &flags_sh);
  const bool w_bf = (fl & 1) != 0;
  const bool s_bf = (fl & 2) != 0;

  const int tx = tid & 15;
  const int ty = tid >> 4;
  const int m0 = blockIdx.x * 64;
  if (tid < 64) vsh[tid] = 0.0f;

  for (int t0 = 0; t0 < SEQ_LEN; t0 += 64) {
    float acc0[4][4] = {{0.f}};
    float acc1[4][4] = {{0.f}};
    int k0 = 0;
#define FUSED_SEGMENT(ACC, KEND)                                                 \
    for (; k0 < (KEND); k0 += 16) {                                              \
      {                                                                          \
        const int r = tid >> 4, c = tid & 15;                                    \
        _Pragma("unroll") for (int j = 0; j < 4; ++j)                            \
            As[c][r + 16 * j] =                                                  \
                load_dyn(W, (size_t)(m0 + r + 16 * j) * N_PRE + k0 + c, w_bf);   \
      }                                                                          \
      {                                                                          \
        const int r = tid >> 6, c = tid & 63;                                    \
        _Pragma("unroll") for (int j = 0; j < 4; ++j)                            \
            Bs[r + 4 * j][c] =                                                   \
                load_dyn(S, (size_t)(k0 + r + 4 * j) * SEQ_LEN + t0 + c, s_bf);  \
      }                                                                          \
      __syncthreads();                                                           \
      _Pragma("unroll") for (int k = 0; k < 16; ++k) {                           \
        _Pragma("unroll") for (int i = 0; i < 4; ++i)                            \
            _Pragma("unroll") for (int j = 0; j < 4; ++j)                        \
                ACC[i][j] += As[k][ty * 4 + i] * Bs[k][tx * 4 + j];              \
      }                                                                          \
      __syncthreads();                                                           \
    }

    FUSED_SEGMENT(acc0, KSPLIT)
    FUSED_SEGMENT(acc1, N_PRE)
#undef FUSED_SEGMENT

#pragma unroll
    for (int i = 0; i < 4; ++i)
#pragma unroll
      for (int j = 0; j < 4; ++j) Ct[ty * 4 + i][tx * 4 + j] = acc0[i][j] + acc1[i][j];
    __syncthreads();
    if (tid < 64) {
      float v = vsh[tid];
#pragma unroll
      for (int k = 0; k < 64; ++k) {
        const float leak = opaque(v * 0.9f);
        v = leak + Ct[tid][k];
        const bool fired = (v >= 1.0f);
        const size_t g = (size_t)(m0 + tid) * SEQ_LEN + t0 + k;
        spk[g] = fired ? 1.0f : 0.0f;
        v = fired ? 0.0f : v;
        vout[g] = v;
      }
      vsh[tid] = v;
    }
    __syncthreads();
  }
}

extern "C" void kernel_launch(void* const* d_in, const int* in_sizes, int n_in,
                              void* d_out, int out_size, void* d_ws, size_t ws_size,
                              hipStream_t stream) {
  const void* stim = d_in[0];
  const void* weights = d_in[1];
  if (n_in >= 2 && in_sizes[0] == N_POST * N_PRE && in_sizes[1] == N_PRE * SEQ_LEN) {
    weights = d_in[0];
    stim = d_in[1];
  }

  float* spk = (float*)d_out;                     // output 0: spikes [N_POST, SEQ_LEN] fp32
  float* vout = spk + (size_t)N_POST * SEQ_LEN;   // output 1: v      [N_POST, SEQ_LEN] fp32

  const size_t carry_bytes = (size_t)N_POST * sizeof(float);
  float* v_carry = nullptr;
  size_t avail = 0;
  if (ws_size > carry_bytes + 8) {
    const size_t coff = (ws_size - carry_bytes) & ~(size_t)15;
    v_carry = (float*)((char*)d_ws + coff);
    avail = coff;
  }
  // Need TWO partial-C buffers (one per K-segment) of N_POST x chunkT fp32.
  int chunkT = (int)((avail / ((size_t)N_POST * sizeof(float) * 2)) / 64 * 64);
  if (chunkT > SEQ_LEN) chunkT = SEQ_LEN;

  if (chunkT >= 64) {
    float* cur = (float*)d_ws;
    for (int t0 = 0; t0 < SEQ_LEN; t0 += chunkT) {
      const int ct = (SEQ_LEN - t0 < chunkT) ? (SEQ_LEN - t0) : chunkT;  // mult of 64
      snn_gemm_v3<<<dim3(ct / 64, N_POST / 128, 2), dim3(128), 0, stream>>>(
          weights, stim, cur, t0, ct);
      snn_scan_v3<<<dim3(N_POST / SCAN_R), dim3(64), 0, stream>>>(
          cur, spk, vout, v_carry, t0, ct, t0 == 0);
    }
  } else {
    snn_fused_blis<<<dim3(N_POST / 64), dim3(256), 0, stream>>>(weights, stim, spk, vout);
  }
}

// Round 3
// 389.657 us; speedup vs baseline: 3.3736x; 3.3736x over previous
//
#include <hip/hip_runtime.h>

#define N_PRE 1024
#define N_POST 2048
#define SEQ_LEN 4096

// Reference-verified numerics (R11 PASS): per C element two fp32 segment
// chains k in [0,512) and [512,1024), ascending, single accumulator each,
// combined rn(S1+S2). stim in {0,1} -> products exact -> FMA == mul+add.
// Scan: v = rn(rn(v*0.9f) + c), fire >= 1.0f, reset 0. DO NOT REORDER.
// v4: split-K over blockIdx.z into C0/C1 (verified correct in v3 run);
// combine rn(S1+S2) in scan staging. GEMM back to v2's register-safe shape:
// 256 thr, 128x128 tile, __launch_bounds__(256,2). v3's (128,4) capped
// unified VGPRs at 128 -> accumulator spill -> 2GB/3.7GB scratch HBM traffic.
#define KSPLIT 512

__device__ __forceinline__ float opaque(float x) {
  asm volatile("" : "+v"(x));
  return x;
}

__device__ __forceinline__ float load_dyn(const void* p, size_t idx, bool isbf) {
  if (isbf) {
    const unsigned short b = ((const unsigned short*)p)[idx];
    return __uint_as_float(((unsigned int)b) << 16);
  }
  return ((const float*)p)[idx];
}

// Input-dtype sniff (established: weights fp32, stim bf16; kept for safety).
__device__ __forceinline__ int sniff_flags(const void* W, const void* S, int tid,
                                           int* flags_sh) {
  if (tid < 64) {
    const unsigned short* uw = (const unsigned short*)W;
    const float f = fabsf(__uint_as_float(((unsigned int)uw[tid * 2]) << 16));
    const bool big = !(f < 64.f);
    const unsigned long long wb = __ballot(big);
    const unsigned short* us = (const unsigned short*)S;
    int hit = 0;
    for (int j = 0; j < 64; ++j) hit |= (us[tid * 128 + 2 * j] == 0x3F80u) ? 1 : 0;
    const unsigned long long sb = __ballot(hit != 0);
    if (tid == 0) *flags_sh = ((wb == 0ull) ? 1 : 0) | ((sb != 0ull) ? 2 : 0);
  }
  __syncthreads();
  return *flags_sh;
}

// ---------------- GEMM v4: 128x128 tile, 8x8 microtile, split-K over z ------
// 256 threads, grid (ct/128, 16, 2) = 1024 blocks -> 4 blocks/CU, 16 waves/CU
// (v2 was 2 blocks/CU at 51% VALUBusy). Single acc[8][8] (64 regs) since each
// block owns one 512-segment; launch_bounds(256,2) = 256-VGPR cap (v2-proven,
// no spill). B-staging packed to b128 writes (conflict fix, v3-verified).
__global__ __launch_bounds__(256, 2) void snn_gemm_v4(const void* __restrict__ W,
                                                      const void* __restrict__ S,
                                                      float* __restrict__ C,
                                                      int t0, int ct) {
  __shared__ float As[16][132];  // [k][m], row 528B: 16B-aligned, 132%32=4
  __shared__ float Bs[16][132];  // [k][t]
  __shared__ int flags_sh;
  const int tid = threadIdx.x;
  const int fl = sniff_flags(W, S, tid, &flags_sh);
  const bool w_bf = (fl & 1) != 0;
  const bool s_bf = (fl & 2) != 0;

  const int tx = tid & 15;   // t dim, 8 cols each
  const int ty = tid >> 4;   // m dim, 8 rows each
  const int m0 = blockIdx.y * 128;
  const int nl0 = blockIdx.x * 128;
  const int kbeg = (int)blockIdx.z * KSPLIT;

  float acc[8][8] = {{0.f}};

  for (int k0 = kbeg; k0 < kbeg + KSPLIT; k0 += 16) {
    // ---- stage A: W[m0..+128][k0..+16] -> As[k][m] ----
    if (!w_bf) {
      const float* Wf = (const float*)W;
      const int row = tid >> 2;       // 0..63
      const int c4 = (tid & 3) * 4;   // 0..12
#pragma unroll
      for (int h = 0; h < 2; ++h) {
        const int m = row + 64 * h;
        const float4 va = *(const float4*)&Wf[(size_t)(m0 + m) * N_PRE + k0 + c4];
        As[c4 + 0][m] = va.x; As[c4 + 1][m] = va.y;
        As[c4 + 2][m] = va.z; As[c4 + 3][m] = va.w;
      }
    } else {
#pragma unroll
      for (int e = 0; e < 8; ++e) {
        const int idx = tid * 8 + e;
        const int m = idx >> 4, c = idx & 15;
        As[c][m] = load_dyn(W, (size_t)(m0 + m) * N_PRE + k0 + c, true);
      }
    }
    // ---- stage B: S[k0..+16][t0+nl0..+128] -> Bs[k][t], b128 writes ----
    {
      const int r = tid >> 4;         // 0..15
      const int c8 = (tid & 15) * 8;  // 0..120
      if (s_bf) {
        const unsigned short* Sb = (const unsigned short*)S;
        const uint4 u =
            *(const uint4*)&Sb[(size_t)(k0 + r) * SEQ_LEN + t0 + nl0 + c8];
        *(float4*)&Bs[r][c8] = make_float4(
            __uint_as_float(u.x << 16), __uint_as_float(u.x & 0xFFFF0000u),
            __uint_as_float(u.y << 16), __uint_as_float(u.y & 0xFFFF0000u));
        *(float4*)&Bs[r][c8 + 4] = make_float4(
            __uint_as_float(u.z << 16), __uint_as_float(u.z & 0xFFFF0000u),
            __uint_as_float(u.w << 16), __uint_as_float(u.w & 0xFFFF0000u));
      } else {
        const float* Sf = (const float*)S;
        const size_t base = (size_t)(k0 + r) * SEQ_LEN + t0 + nl0 + c8;
        *(float4*)&Bs[r][c8] = *(const float4*)&Sf[base];
        *(float4*)&Bs[r][c8 + 4] = *(const float4*)&Sf[base + 4];
      }
    }
    __syncthreads();
#pragma unroll
    for (int k = 0; k < 16; ++k) {
      float a[8], b[8];
      *(float4*)&a[0] = *(const float4*)&As[k][ty * 8];
      *(float4*)&a[4] = *(const float4*)&As[k][ty * 8 + 4];
      *(float4*)&b[0] = *(const float4*)&Bs[k][tx * 8];
      *(float4*)&b[4] = *(const float4*)&Bs[k][tx * 8 + 4];
#pragma unroll
      for (int i = 0; i < 8; ++i)
#pragma unroll
        for (int j = 0; j < 8; ++j)
          acc[i][j] += a[i] * b[j];  // exact product: add-chain only
    }
    __syncthreads();
  }

  float* Cseg = C + (size_t)blockIdx.z * N_POST * (size_t)ct;
#pragma unroll
  for (int i = 0; i < 8; ++i) {
    float* dst = &Cseg[(size_t)(m0 + ty * 8 + i) * ct + nl0 + tx * 8];
    *(float4*)&dst[0] = make_float4(acc[i][0], acc[i][1], acc[i][2], acc[i][3]);
    *(float4*)&dst[4] = make_float4(acc[i][4], acc[i][5], acc[i][6], acc[i][7]);
  }
}

// ---------------- Scan v3: single-wave blocks, 8 neurons, no barriers -------
// 256 blocks x 64 threads. Wave-lockstep makes LDS cross-lane coherent
// without __syncthreads. Prefetch loads issued BEFORE the scan chain,
// ds_writes AFTER it (latency hides under the 1024-cyc chain). The combine
// c = rn(C0 + C1) == rn(S1+S2) happens here, off the critical v-chain
// (verified bit-exact in v3 run: absmax unchanged).
#define SCAN_R 8
#define SCAN_T 64
#define SCAN_P 68  // row stride 272B: 16B-aligned, 68%32=4 bank spread
__global__ __launch_bounds__(64) void snn_scan_v3(const float* __restrict__ C,
                                                  float* __restrict__ spk,
                                                  float* __restrict__ vout,
                                                  float* __restrict__ v_carry,
                                                  int t0, int ct, int first) {
  __shared__ float c_t[2][SCAN_R][SCAN_P];
  const int l = threadIdx.x;
  const int n0 = blockIdx.x * SCAN_R;
  const float* C1 = C + (size_t)N_POST * (size_t)ct;

  float v = 0.0f;
  if (l < SCAN_R && !first) v = v_carry[n0 + l];

  const int r0 = l >> 4;        // 0..3
  const int c4 = (l & 15) * 4;  // 0..60
  const int ntiles = ct / SCAN_T;

  // prologue: stage tile 0 (combine S1+S2 during staging)
#pragma unroll
  for (int h = 0; h < 2; ++h) {
    const int r = r0 + 4 * h;
    const size_t g = (size_t)(n0 + r) * ct + c4;
    const float4 a = *(const float4*)&C[g];
    const float4 b = *(const float4*)&C1[g];
    *(float4*)&c_t[0][r][c4] =
        make_float4(a.x + b.x, a.y + b.y, a.z + b.z, a.w + b.w);
  }

  int buf = 0;
  for (int it = 0; it < ntiles; ++it) {
    // issue next-tile loads now (complete under the scan chain)
    float4 pa[2], pb[2];
    const bool pf = (it + 1 < ntiles);
    if (pf) {
#pragma unroll
      for (int h = 0; h < 2; ++h) {
        const int r = r0 + 4 * h;
        const size_t g = (size_t)(n0 + r) * ct + (size_t)(it + 1) * SCAN_T + c4;
        pa[h] = *(const float4*)&C[g];
        pb[h] = *(const float4*)&C1[g];
      }
    }
    if (l < SCAN_R) {
      const size_t gout = (size_t)(n0 + l) * SEQ_LEN + t0 + (size_t)it * SCAN_T;
#pragma unroll
      for (int g = 0; g < SCAN_T / 16; ++g) {
        float c[16];
        *(float4*)&c[0] = *(const float4*)&c_t[buf][l][g * 16];
        *(float4*)&c[4] = *(const float4*)&c_t[buf][l][g * 16 + 4];
        *(float4*)&c[8] = *(const float4*)&c_t[buf][l][g * 16 + 8];
        *(float4*)&c[12] = *(const float4*)&c_t[buf][l][g * 16 + 12];
        float s[16], vv[16];
#pragma unroll
        for (int k = 0; k < 16; ++k) {
          const float leak = opaque(v * 0.9f);  // rn(v*0.9f)
          v = leak + c[k];                      // rn(+c)
          const bool fired = (v >= 1.0f);
          s[k] = fired ? 1.0f : 0.0f;
          v = fired ? 0.0f : v;
          vv[k] = v;
        }
#pragma unroll
        for (int q = 0; q < 4; ++q) {
          *(float4*)&spk[gout + g * 16 + q * 4] =
              make_float4(s[q * 4], s[q * 4 + 1], s[q * 4 + 2], s[q * 4 + 3]);
          *(float4*)&vout[gout + g * 16 + q * 4] =
              make_float4(vv[q * 4], vv[q * 4 + 1], vv[q * 4 + 2], vv[q * 4 + 3]);
        }
      }
    }
    // land the prefetch into the other buffer (vmcnt wait happens here,
    // after the chain, not before it)
    if (pf) {
#pragma unroll
      for (int h = 0; h < 2; ++h) {
        const int r = r0 + 4 * h;
        *(float4*)&c_t[buf ^ 1][r][c4] =
            make_float4(pa[h].x + pb[h].x, pa[h].y + pb[h].y, pa[h].z + pb[h].z,
                        pa[h].w + pb[h].w);
      }
    }
    buf ^= 1;
  }
  if (l < SCAN_R) v_carry[n0 + l] = v;
}

// ---------------- fused fallback (ws too small), same [512|512] chain -------
__global__ __launch_bounds__(256) void snn_fused_blis(const void* __restrict__ W,
                                                      const void* __restrict__ S,
                                                      float* __restrict__ spk,
                                                      float* __restrict__ vout) {
  __shared__ float As[16][68];
  __shared__ float Bs[16][68];
  __shared__ float Ct[64][65];
  __shared__ float vsh[64];
  __shared__ int flags_sh;
  const int tid = threadIdx.x;
  const int fl = sniff_flags(W, S, tid, &flags_sh);
  const bool w_bf = (fl & 1) != 0;
  const bool s_bf = (fl & 2) != 0;

  const int tx = tid & 15;
  const int ty = tid >> 4;
  const int m0 = blockIdx.x * 64;
  if (tid < 64) vsh[tid] = 0.0f;

  for (int t0 = 0; t0 < SEQ_LEN; t0 += 64) {
    float acc0[4][4] = {{0.f}};
    float acc1[4][4] = {{0.f}};
    int k0 = 0;
#define FUSED_SEGMENT(ACC, KEND)                                                 \
    for (; k0 < (KEND); k0 += 16) {                                              \
      {                                                                          \
        const int r = tid >> 4, c = tid & 15;                                    \
        _Pragma("unroll") for (int j = 0; j < 4; ++j)                            \
            As[c][r + 16 * j] =                                                  \
                load_dyn(W, (size_t)(m0 + r + 16 * j) * N_PRE + k0 + c, w_bf);   \
      }                                                                          \
      {                                                                          \
        const int r = tid >> 6, c = tid & 63;                                    \
        _Pragma("unroll") for (int j = 0; j < 4; ++j)                            \
            Bs[r + 4 * j][c] =                                                   \
                load_dyn(S, (size_t)(k0 + r + 4 * j) * SEQ_LEN + t0 + c, s_bf);  \
      }                                                                          \
      __syncthreads();                                                           \
      _Pragma("unroll") for (int k = 0; k < 16; ++k) {                           \
        _Pragma("unroll") for (int i = 0; i < 4; ++i)                            \
            _Pragma("unroll") for (int j = 0; j < 4; ++j)                        \
                ACC[i][j] += As[k][ty * 4 + i] * Bs[k][tx * 4 + j];              \
      }                                                                          \
      __syncthreads();                                                           \
    }

    FUSED_SEGMENT(acc0, KSPLIT)
    FUSED_SEGMENT(acc1, N_PRE)
#undef FUSED_SEGMENT

#pragma unroll
    for (int i = 0; i < 4; ++i)
#pragma unroll
      for (int j = 0; j < 4; ++j) Ct[ty * 4 + i][tx * 4 + j] = acc0[i][j] + acc1[i][j];
    __syncthreads();
    if (tid < 64) {
      float v = vsh[tid];
#pragma unroll
      for (int k = 0; k < 64; ++k) {
        const float leak = opaque(v * 0.9f);
        v = leak + Ct[tid][k];
        const bool fired = (v >= 1.0f);
        const size_t g = (size_t)(m0 + tid) * SEQ_LEN + t0 + k;
        spk[g] = fired ? 1.0f : 0.0f;
        v = fired ? 0.0f : v;
        vout[g] = v;
      }
      vsh[tid] = v;
    }
    __syncthreads();
  }
}

extern "C" void kernel_launch(void* const* d_in, const int* in_sizes, int n_in,
                              void* d_out, int out_size, void* d_ws, size_t ws_size,
                              hipStream_t stream) {
  const void* stim = d_in[0];
  const void* weights = d_in[1];
  if (n_in >= 2 && in_sizes[0] == N_POST * N_PRE && in_sizes[1] == N_PRE * SEQ_LEN) {
    weights = d_in[0];
    stim = d_in[1];
  }

  float* spk = (float*)d_out;                     // output 0: spikes [N_POST, SEQ_LEN] fp32
  float* vout = spk + (size_t)N_POST * SEQ_LEN;   // output 1: v      [N_POST, SEQ_LEN] fp32

  const size_t carry_bytes = (size_t)N_POST * sizeof(float);
  float* v_carry = nullptr;
  size_t avail = 0;
  if (ws_size > carry_bytes + 8) {
    const size_t coff = (ws_size - carry_bytes) & ~(size_t)15;
    v_carry = (float*)((char*)d_ws + coff);
    avail = coff;
  }
  // Need TWO partial-C buffers (one per K-segment) of N_POST x chunkT fp32.
  int chunkT = (int)((avail / ((size_t)N_POST * sizeof(float) * 2)) / 128 * 128);
  if (chunkT > SEQ_LEN) chunkT = SEQ_LEN;

  if (chunkT >= 128) {
    float* cur = (float*)d_ws;
    for (int t0 = 0; t0 < SEQ_LEN; t0 += chunkT) {
      const int ct = (SEQ_LEN - t0 < chunkT) ? (SEQ_LEN - t0) : chunkT;  // mult of 128
      snn_gemm_v4<<<dim3(ct / 128, N_POST / 128, 2), dim3(256), 0, stream>>>(
          weights, stim, cur, t0, ct);
      snn_scan_v3<<<dim3(N_POST / SCAN_R), dim3(64), 0, stream>>>(
          cur, spk, vout, v_carry, t0, ct, t0 == 0);
    }
  } else {
    snn_fused_blis<<<dim3(N_POST / 64), dim3(256), 0, stream>>>(weights, stim, spk, vout);
  }
}